// Round 4
// baseline (444.560 us; speedup 1.0000x reference)
//
#include <hip/hip_runtime.h>
#include <hip/hip_bf16.h>

#define N_PTS 1500000
#define NT_TILES (N_PTS / 16)   // 93750, exact
#define CBCH 96
#define CTCH 128
#define COCH 96
#define NB 8
#define BN_EPS 1e-5f
#define GRID1 512               // 2 blocks/CU x 256 CU -> all co-resident (launch_bounds(256,2))
#define NWAVE (GRID1 * 4)
#define STPAD 100               // sT row stride (floats)

// ws float offsets
#define GSUM_OFF 0
#define GSQ_OFF 96
#define BAR_OFF 192             // int barrier counter

typedef __attribute__((ext_vector_type(8))) short bf16x8;
typedef __attribute__((ext_vector_type(4))) float f32x4;

__device__ __forceinline__ short f2bf(float f) {
    __hip_bfloat16 h = __float2bfloat16(f);   // native cvt, RNE
    short s;
    __builtin_memcpy(&s, &h, sizeof(s));
    return s;
}

// k0z: zero stats accumulators + barrier counter (each launch, before fused kernel).
__global__ void k0z(float* __restrict__ ws) {
    if (threadIdx.x < 256) ws[threadIdx.x] = 0.f;
}

// ---------------------------------------------------------------------------
// MFMA 16x16x32 bf16 mapping: A lane(l): row=l&15, k=8*(l>>4)+j ;
// B lane(l): col=l&15, k=8*(l>>4)+j ; D lane(l): col=l&15, row=4*(l>>4)+reg
// Swapped form: A = W^T fragment (row=channel), B = points (col=point).
// Lane (grp,lr) owns channels ct*16+grp*4+[0..3] of point base+lr.

__device__ __forceinline__ void stage_W(const float* __restrict__ W, short* sW) {
    for (int i = threadIdx.x; i < CBCH * COCH; i += blockDim.x) {
        int k = i / COCH, c = i % COCH;               // W[k][c], coalesced read
        int ct = c >> 4, lr = c & 15;
        int kt = k >> 5, grp = (k >> 3) & 3, j = k & 7;
        sW[(((ct * 3 + kt) * 64) + (grp * 16 + lr)) * 8 + j] = f2bf(W[i]);
    }
}

__device__ __forceinline__ void load_bfrag_lds(const short* sW, int lane, bf16x8 bf[6][3]) {
    #pragma unroll
    for (int ct = 0; ct < 6; ++ct)
        #pragma unroll
        for (int kt = 0; kt < 3; ++kt)
            bf[ct][kt] = *reinterpret_cast<const bf16x8*>(sW + ((ct * 3 + kt) * 64 + lane) * 8);
}

template <bool NTLOAD>
__device__ __forceinline__ void tile_acc(const float* __restrict__ bb,
                                         const int* __restrict__ bidx,
                                         const float* __restrict__ sT,
                                         const bf16x8 bf[6][3],
                                         int base, int grp, int lr,
                                         f32x4 acc[6]) {
    int b = bidx[base + lr];
    #pragma unroll
    for (int ct = 0; ct < 6; ++ct)
        acc[ct] = *reinterpret_cast<const f32x4*>(&sT[b * STPAD + ct * 16 + grp * 4]);

    bf16x8 pf[3];
    #pragma unroll
    for (int kt = 0; kt < 3; ++kt) {
        const f32x4* p = reinterpret_cast<const f32x4*>(bb + (size_t)(base + lr) * CBCH + kt * 32 + grp * 8);
        f32x4 x0, x1;
        if (NTLOAD) { x0 = __builtin_nontemporal_load(p); x1 = __builtin_nontemporal_load(p + 1); }
        else        { x0 = p[0]; x1 = p[1]; }
        #pragma unroll
        for (int j = 0; j < 4; ++j) {
            pf[kt][j]     = f2bf(x0[j]);
            pf[kt][4 + j] = f2bf(x1[j]);
        }
    }
    #pragma unroll
    for (int ct = 0; ct < 6; ++ct)
        #pragma unroll
        for (int kt = 0; kt < 3; ++kt)
            acc[ct] = __builtin_amdgcn_mfma_f32_16x16x32_bf16(bf[ct][kt], pf[kt], acc[ct], 0, 0, 0);
}

// Fused: pass1 stats -> grid barrier -> pass2 normalize+ReLU+store.
__global__ __launch_bounds__(256, 2) void fused(const float* __restrict__ bb,
                                                const int* __restrict__ bidx,
                                                const float* __restrict__ text,
                                                const float* __restrict__ W,
                                                const float* __restrict__ gamma,
                                                const float* __restrict__ beta,
                                                float* __restrict__ ws,
                                                float* __restrict__ out) {
    __shared__ __align__(16) short sW[6 * 3 * 64 * 8];   // 18 KB
    __shared__ __align__(16) float sT[NB * STPAD];
    __shared__ float sredS[4][COCH];
    __shared__ float sredQ[4][COCH];
    __shared__ __align__(16) float sScale[COCH];
    __shared__ __align__(16) float sBias[COCH];

    stage_W(W, sW);
    // per-block T = text @ W[96:224,:]  (reads are L2/L3-resident after first blocks)
    for (int i = threadIdx.x; i < NB * COCH; i += blockDim.x) {
        int b = i / COCH, c = i % COCH;
        float acc = 0.f;
        #pragma unroll 8
        for (int k = 0; k < CTCH; ++k)
            acc += text[b * CTCH + k] * W[(CBCH + k) * COCH + c];
        sT[b * STPAD + c] = acc;
    }
    __syncthreads();

    const int lane = threadIdx.x & 63;
    const int wv = threadIdx.x >> 6;
    const int grp = lane >> 4, lr = lane & 15;

    bf16x8 bf[6][3];
    load_bfrag_lds(sW, lane, bf);

    const int gw = blockIdx.x * 4 + wv;

    // ---- pass 1: stats (forward order; normal loads populate L3) ----
    {
        f32x4 sum[6], sq[6];
        #pragma unroll
        for (int ct = 0; ct < 6; ++ct) { sum[ct] = (f32x4)0.f; sq[ct] = (f32x4)0.f; }

        for (int t = gw; t < NT_TILES; t += NWAVE) {
            int base = t * 16;
            f32x4 acc[6];
            tile_acc<false>(bb, bidx, sT, bf, base, grp, lr, acc);
            #pragma unroll
            for (int ct = 0; ct < 6; ++ct) {
                sum[ct] += acc[ct];
                sq[ct] += acc[ct] * acc[ct];
            }
        }
        #pragma unroll
        for (int ct = 0; ct < 6; ++ct)
            #pragma unroll
            for (int r = 0; r < 4; ++r) {
                float s = sum[ct][r], q = sq[ct][r];
                s += __shfl_xor(s, 1);  q += __shfl_xor(q, 1);
                s += __shfl_xor(s, 2);  q += __shfl_xor(q, 2);
                s += __shfl_xor(s, 4);  q += __shfl_xor(q, 4);
                s += __shfl_xor(s, 8);  q += __shfl_xor(q, 8);
                if (lr == 0) {
                    sredS[wv][ct * 16 + grp * 4 + r] = s;
                    sredQ[wv][ct * 16 + grp * 4 + r] = q;
                }
            }
        __syncthreads();
        if (threadIdx.x < COCH) {
            int c = threadIdx.x;
            atomicAdd(&ws[GSUM_OFF + c], sredS[0][c] + sredS[1][c] + sredS[2][c] + sredS[3][c]);
            atomicAdd(&ws[GSQ_OFF + c],  sredQ[0][c] + sredQ[1][c] + sredQ[2][c] + sredQ[3][c]);
        }
    }

    // ---- grid barrier (all 512 blocks co-resident by construction) ----
    __syncthreads();   // drains this block's atomics (vmcnt(0) before s_barrier)
    if (threadIdx.x == 0) {
        int* bar = (int*)&ws[BAR_OFF];
        __hip_atomic_fetch_add(bar, 1, __ATOMIC_ACQ_REL, __HIP_MEMORY_SCOPE_AGENT);
        while (__hip_atomic_load(bar, __ATOMIC_ACQUIRE, __HIP_MEMORY_SCOPE_AGENT) < GRID1) {}
    }
    __syncthreads();

    // ---- finalize scale/bias (coherent loads; other XCDs wrote the sums) ----
    if (threadIdx.x < COCH) {
        int c = threadIdx.x;
        float s = __hip_atomic_load(&ws[GSUM_OFF + c], __ATOMIC_RELAXED, __HIP_MEMORY_SCOPE_AGENT);
        float q = __hip_atomic_load(&ws[GSQ_OFF + c],  __ATOMIC_RELAXED, __HIP_MEMORY_SCOPE_AGENT);
        float mean = s * (1.f / (float)N_PTS);
        float var  = q * (1.f / (float)N_PTS) - mean * mean;
        float scl  = gamma[c] * rsqrtf(var + BN_EPS);
        sScale[c] = scl;
        sBias[c]  = beta[c] - mean * scl;
    }
    __syncthreads();

    f32x4 sc[6], bs[6];
    #pragma unroll
    for (int ct = 0; ct < 6; ++ct) {
        sc[ct] = *reinterpret_cast<const f32x4*>(&sScale[ct * 16 + grp * 4]);
        bs[ct] = *reinterpret_cast<const f32x4*>(&sBias[ct * 16 + grp * 4]);
    }

    // ---- pass 2: reverse order (hit pass-1's L3 tail), NT loads (no-allocate
    // preserves the resident tail), NT stores (writes don't evict it) ----
    for (int t = NT_TILES - 1 - gw; t >= 0; t -= NWAVE) {
        int base = t * 16;
        f32x4 acc[6];
        tile_acc<true>(bb, bidx, sT, bf, base, grp, lr, acc);
        #pragma unroll
        for (int ct = 0; ct < 6; ++ct) {
            f32x4 y;
            #pragma unroll
            for (int r = 0; r < 4; ++r)
                y[r] = fmaxf(acc[ct][r] * sc[ct][r] + bs[ct][r], 0.f);
            __builtin_nontemporal_store(y,
                reinterpret_cast<f32x4*>(out + (size_t)(base + lr) * COCH + ct * 16 + grp * 4));
        }
    }
}

extern "C" void kernel_launch(void* const* d_in, const int* in_sizes, int n_in,
                              void* d_out, int out_size, void* d_ws, size_t ws_size,
                              hipStream_t stream) {
    const float* bb    = (const float*)d_in[0];
    const int*   bidx  = (const int*)d_in[1];
    const float* text  = (const float*)d_in[2];
    const float* W     = (const float*)d_in[3];
    const float* gamma = (const float*)d_in[4];
    const float* beta  = (const float*)d_in[5];
    float* out = (float*)d_out;
    float* ws  = (float*)d_ws;

    hipLaunchKernelGGL(k0z, dim3(1), dim3(256), 0, stream, ws);
    hipLaunchKernelGGL(fused, dim3(GRID1), dim3(256), 0, stream,
                       bb, bidx, text, W, gamma, beta, ws, out);
}